// Round 10
// baseline (193.285 us; speedup 1.0000x reference)
//
#include <hip/hip_runtime.h>
#include <hip/hip_bf16.h>

typedef __attribute__((ext_vector_type(8))) short short8;   // 8 bf16 = 4 VGPR (MFMA A/B frag)
typedef __attribute__((ext_vector_type(4))) float f32x4;    // MFMA C/D frag

__device__ __forceinline__ unsigned short f2bf(float f) {
    union { __hip_bfloat16 h; unsigned short u; } cv;
    cv.h = __float2bfloat16(f);   // RNE
    return cv.u;
}

// jax.nn.gelu(approximate=True): 0.5x(1+tanh(sqrt(2/pi)(x+0.044715x^3))) == x*e/(e+1), e=exp(2*inner)
__device__ __forceinline__ float gelu_t(float x) {
    float e = __expf(1.5957691216057308f * x * __builtin_fmaf(0.044715f, x * x, 1.0f));
    return x * (e / (e + 1.0f));
}

__device__ __forceinline__ void gload_lds16(const void* g, void* l) {
    __builtin_amdgcn_global_load_lds((const __attribute__((address_space(1))) unsigned int*)g,
                                     (__attribute__((address_space(3))) unsigned int*)l, 16, 0, 0);
}

// XOR swizzle key for 64B LDS slices (conflicts==0 measured R3/R5)
__device__ __forceinline__ int swzkey(int r) { return ((r >> 1) & 3) << 4; }

// ---------------------------------------------------------------------------
// Launch 1: transpose + f32->bf16 + pre-swizzle for We, Wd only (z = 0/1).
// (verified R3-R9; W2 moved to prep2)
// ---------------------------------------------------------------------------
__global__ __launch_bounds__(256) void transpose_wewd(const float* __restrict__ W1,
                                                      unsigned short* __restrict__ Wet,
                                                      unsigned short* __restrict__ Wdt) {
    int z = blockIdx.z;
    const float* in = (z == 0) ? W1 : (W1 + 512 * 512);
    unsigned short* out = (z == 0) ? Wet : Wdt;
    const int N = 512;

    __shared__ float tile[64][65];
    int k0 = blockIdx.x * 64, n0 = blockIdx.y * 64;
    int t = threadIdx.x;
    int c = t & 63, r0 = t >> 6;
#pragma unroll
    for (int i = 0; i < 16; i++) {
        int r = r0 + i * 4;
        tile[r][c] = in[(size_t)(k0 + r) * N + n0 + c];
    }
    __syncthreads();
    int kk = t & 15;
    int nl0 = t >> 4;
#pragma unroll
    for (int i = 0; i < 4; i++) {
        int nl = nl0 + i * 16;
        int n  = n0 + nl;
        unsigned short b0 = f2bf(tile[kk * 4 + 0][nl]);
        unsigned short b1 = f2bf(tile[kk * 4 + 1][nl]);
        unsigned short b2 = f2bf(tile[kk * 4 + 2][nl]);
        unsigned short b3 = f2bf(tile[kk * 4 + 3][nl]);
        uint2 v;
        v.x = (unsigned)b0 | ((unsigned)b1 << 16);
        v.y = (unsigned)b2 | ((unsigned)b3 << 16);
        int byte_in_chunk = kk * 8;
        int slice = byte_in_chunk & ~63;
        int off   = (byte_in_chunk & 63) ^ swzkey(n);
        size_t obyte = (size_t)n * 1024 + (size_t)k0 * 2 + slice + off;
        *(uint2*)((char*)out + obyte) = v;
    }
}

// ---------------------------------------------------------------------------
// Launch 2 (prep2): one launch, two independent jobs by blockIdx.x:
//   bx <  128 : W2 transpose -> W2t (verified z==2 path, retiled)
//   bx >= 128 : he/hd GEMM at BM=64 BN=64 (176 blocks vs old 44 — 4x spread).
//               Same verified staging / gload_lds / swizzle / frag patterns.
// ---------------------------------------------------------------------------
__global__ __launch_bounds__(256) void prep2(const float* __restrict__ enc,
                                             const float* __restrict__ dec,
                                             const float* __restrict__ W2,
                                             const unsigned short* __restrict__ Wet,
                                             const unsigned short* __restrict__ Wdt,
                                             const float* __restrict__ b1,
                                             unsigned short* __restrict__ W2t,
                                             float* __restrict__ he,
                                             float* __restrict__ hd) {
    __shared__ alignas(16) char pbuf[16640];   // union: tile[64][65]f32 | As(4K)+Bs(4K)
    int t = threadIdx.x;
    int bx = blockIdx.x;

    if (bx < 128) {
        // ---- W2 transpose: K=512 (8 k-tiles), N=1024 (16 n-tiles)
        float (*tile)[65] = (float(*)[65])pbuf;
        int k0 = (bx & 7) * 64, n0 = (bx >> 3) * 64;
        int c = t & 63, r0 = t >> 6;
#pragma unroll
        for (int i = 0; i < 16; i++) {
            int r = r0 + i * 4;
            tile[r][c] = W2[(size_t)(k0 + r) * 1024 + n0 + c];
        }
        __syncthreads();
        int kk = t & 15;
        int nl0 = t >> 4;
#pragma unroll
        for (int i = 0; i < 4; i++) {
            int nl = nl0 + i * 16;
            int n  = n0 + nl;
            unsigned short b0 = f2bf(tile[kk * 4 + 0][nl]);
            unsigned short b1 = f2bf(tile[kk * 4 + 1][nl]);
            unsigned short b2 = f2bf(tile[kk * 4 + 2][nl]);
            unsigned short b3 = f2bf(tile[kk * 4 + 3][nl]);
            uint2 v;
            v.x = (unsigned)b0 | ((unsigned)b1 << 16);
            v.y = (unsigned)b2 | ((unsigned)b3 << 16);
            int byte_in_chunk = kk * 8;
            int slice = byte_in_chunk & ~63;
            int off   = (byte_in_chunk & 63) ^ swzkey(n);
            size_t obyte = (size_t)n * 1024 + (size_t)k0 * 2 + slice + off;
            *(uint2*)((char*)W2t + obyte) = v;
        }
        return;
    }

    // ---- he/hd GEMM: BM=64 BN=64 BK=32, 4 waves 2m x 2n (wave 32x32, acc[2][2])
    int id  = bx - 128;                 // 0..175
    int ny  = id & 7;                   // n-tile (512/64)
    int mid = id >> 3;                  // 0..21: <16 enc, else dec
    bool isEnc = mid < 16;
    const float* A = isEnc ? enc : dec;
    const unsigned short* Bt = isEnc ? Wet : Wdt;
    const float* bias = isEnc ? b1 : nullptr;
    float* C = isEnc ? he : hd;
    size_t m0 = (size_t)(isEnc ? mid : mid - 16) * 64;
    int n0 = ny * 64;

    unsigned short* As = (unsigned short*)pbuf;          // 64 x 64B = 4KB
    unsigned short* Bs = (unsigned short*)(pbuf + 4096); // 64 x 64B = 4KB
    int lane = t & 63, w = t >> 6;
    int wm = w >> 1, wn = w & 1;
    int rA = t >> 3, cg = t & 7;
    f32x4 acc[2][2] = {};

    for (int kt = 0; kt < 16; ++kt) {
        int k0 = kt * 32;
        __syncthreads();
        // stage A (f32 -> bf16, swizzled) — verified pattern, 2 passes of 32 rows
#pragma unroll
        for (int p = 0; p < 2; p++) {
            int r = rA + p * 32;
            f32x4 v = *(const f32x4*)&A[(m0 + r) * 512 + k0 + cg * 4];
            uint2 pk;
            pk.x = (unsigned)f2bf(v.x) | ((unsigned)f2bf(v.y) << 16);
            pk.y = (unsigned)f2bf(v.z) | ((unsigned)f2bf(v.w) << 16);
            int off = (cg * 8) ^ swzkey(r);
            *(uint2*)((char*)As + r * 64 + off) = pk;
        }
        // stage B: 4KB via gload_lds, wave w covers rows [w*16, w*16+16)
        {
            int ibyte = w * 1024;
            int lb = ibyte + lane * 16;
            int row = lb >> 6, colb = lb & 63;
            const char* src = (const char*)Bt + (size_t)(n0 + row) * 1024 + k0 * 2 + colb;
            gload_lds16(src, (char*)Bs + ibyte);
        }
        __syncthreads();
        short8 af[2], bf[2];
#pragma unroll
        for (int mi = 0; mi < 2; mi++) {
            int r = wm * 32 + mi * 16 + (lane & 15);
            int off = ((lane >> 4) * 16) ^ swzkey(r);
            af[mi] = *(const short8*)((const char*)As + r * 64 + off);
        }
#pragma unroll
        for (int ni = 0; ni < 2; ni++) {
            int n = wn * 32 + ni * 16 + (lane & 15);
            int off = ((lane >> 4) * 16) ^ swzkey(n);
            bf[ni] = *(const short8*)((const char*)Bs + n * 64 + off);
        }
#pragma unroll
        for (int mi = 0; mi < 2; mi++)
#pragma unroll
            for (int ni = 0; ni < 2; ni++)
                acc[mi][ni] = __builtin_amdgcn_mfma_f32_16x16x32_bf16(af[mi], bf[ni], acc[mi][ni], 0, 0, 0);
    }
#pragma unroll
    for (int mi = 0; mi < 2; mi++) {
        int row = wm * 32 + mi * 16 + ((lane >> 4) << 2);
#pragma unroll
        for (int ni = 0; ni < 2; ni++) {
            int col = n0 + wn * 32 + ni * 16 + (lane & 15);
            float bv = bias ? bias[col] : 0.0f;
#pragma unroll
            for (int q = 0; q < 4; q++)
                C[(m0 + row + q) * 512 + col] = acc[mi][ni][q] + bv;
        }
    }
}

// ---------------------------------------------------------------------------
// Fused joint: out[m][v] = gelu(he[t(m)]+hd[b,u(m)]) @ W2.   (R9 structure,
// best measured; ONLY change: setprio removed — m190: harmful in lockstep.)
// BM=64 BN=512 BK=32, 512 thr, 8 waves 1m x 8n (wave 64x64, acc[4][4]).
// dbuf A+B, counted vmcnt(2), one barrier/step, LDS-pad epilogue, NT stores.
// ---------------------------------------------------------------------------
__global__ __launch_bounds__(512, 4) void joint_fused(const float* __restrict__ he,
                                                      const float* __restrict__ hd,
                                                      const unsigned short* __restrict__ W2t,
                                                      float* __restrict__ out) {
    __shared__ alignas(16) char lds[73728];
    // carve: As[0]=0, As[1]=4096, Bs[0]=8192, Bs[1]=40960   (A 4KB x2, B 32KB x2)
    int t = threadIdx.x;
    int lane = t & 63, w = t >> 6;
    int bx = blockIdx.x;                   // 0..1535, XCD-swizzle (1536 % 8 == 0 -> bijective)
    int mt = (bx & 7) * 192 + (bx >> 3);
    size_t m0 = (size_t)mt * 64;
    int n0 = blockIdx.y * 512;

    // ---- A-gen mapping (fixed per thread): row rA = t>>3, 4 k's at cg*4 (verified R5)
    int rA = t >> 3, cg = t & 7;
    int mrow = (int)m0 + rA;
    int tI = mrow / 96;                    // b*256+t index into he (0..1023)
    int u  = mrow - tI * 96;
    const float* eP = he + (size_t)tI * 512 + cg * 4;
    const float* dP = hd + (size_t)((tI >> 8) * 96 + u) * 512 + cg * 4;
    int aoff = rA * 64 + ((cg * 8) ^ swzkey(rA));

    // ---- B staging: wave w covers Bs rows [w*64, w*64+64), 4 x 1KB insts (verified R5)
    const char* bSrc[4];
#pragma unroll
    for (int i = 0; i < 4; i++) {
        int row = w * 64 + i * 16 + (lane >> 2);
        bSrc[i] = (const char*)W2t + (size_t)(n0 + row) * 1024 + (lane & 3) * 16;
    }

    // ---- fragment byte offsets: 1m x 8n (wave owns all 64 rows, cols w*64..w*64+63)
    int l15 = lane & 15, lg = lane >> 4;
    int aOff[4], bOff[4];
#pragma unroll
    for (int mi = 0; mi < 4; mi++) {
        int r = mi * 16 + l15;
        aOff[mi] = r * 64 + ((lg * 16) ^ swzkey(r));
    }
#pragma unroll
    for (int ni = 0; ni < 4; ni++) {
        int n = w * 64 + ni * 16 + l15;
        bOff[ni] = 8192 + n * 64 + ((lg * 16) ^ swzkey(n));   // +Bs base
    }

    f32x4 acc[4][4] = {};
    f32x4 er[2], dr[2];                    // 2-slot rotation, static idx (unrolled)

#define LOADED(slot, kt)  do { \
        er[slot] = *(const f32x4*)(eP + (kt) * 32); \
        dr[slot] = *(const f32x4*)(dP + (kt) * 32); } while (0)

#define STAGE_B(buf, kt)  do { \
        _Pragma("unroll") \
        for (int i = 0; i < 4; i++) \
            gload_lds16(bSrc[i] + (kt) * 64, lds + 8192 + (buf) * 32768 + w * 4096 + i * 1024); } while (0)

#define GELU_A(buf, slot) do { \
        uint2 pk; \
        pk.x = (unsigned)f2bf(gelu_t(er[slot].x + dr[slot].x)) | \
               ((unsigned)f2bf(gelu_t(er[slot].y + dr[slot].y)) << 16); \
        pk.y = (unsigned)f2bf(gelu_t(er[slot].z + dr[slot].z)) | \
               ((unsigned)f2bf(gelu_t(er[slot].w + dr[slot].w)) << 16); \
        *(uint2*)(lds + (buf) * 4096 + aoff) = pk; } while (0)

    // ---- prologue: B(0) staged, regs tile0+tile1 in flight, A(0) written
    STAGE_B(0, 0);
    LOADED(0, 0);
    LOADED(1, 1);
    GELU_A(0, 0);                          // auto-wait drains slot-0 regs (B(0) older -> done)
    asm volatile("s_waitcnt lgkmcnt(0)" ::: "memory");
    asm volatile("s_waitcnt vmcnt(2)" ::: "memory");   // B(0) landed; tile-1 regs may fly
    __builtin_amdgcn_sched_barrier(0);
    __builtin_amdgcn_s_barrier();
    __builtin_amdgcn_sched_barrier(0);

#pragma unroll
    for (int kt = 0; kt < 16; ++kt) {
        const int cur = kt & 1, nxt = cur ^ 1;
        // issue next-tile staging and next-next reg loads first (fly under compute)
        if (kt < 15) STAGE_B(nxt, kt + 1);
        if (kt < 14) LOADED(cur, kt + 2);                 // slot kt&1 free: consumed last step
        if (kt < 15) GELU_A(nxt, nxt);                    // A(kt+1) from regs slot (kt+1)&1
        // fragments + MFMA from cur
        short8 a[4];
#pragma unroll
        for (int mi = 0; mi < 4; mi++) a[mi] = *(const short8*)(lds + cur * 4096 + aOff[mi]);
#pragma unroll
        for (int ni = 0; ni < 4; ni++) {
            short8 b = *(const short8*)(lds + cur * 32768 + bOff[ni]);
#pragma unroll
            for (int mi = 0; mi < 4; mi++)
                acc[mi][ni] = __builtin_amdgcn_mfma_f32_16x16x32_bf16(a[mi], b, acc[mi][ni], 0, 0, 0);
        }
        if (kt < 15) {
            // own frag reads + A(nxt) ds_write done; B(nxt) landed; reg loads stay in flight
            asm volatile("s_waitcnt lgkmcnt(0)" ::: "memory");
            __builtin_amdgcn_sched_barrier(0);
            if (kt < 14) asm volatile("s_waitcnt vmcnt(2)" ::: "memory");
            else         asm volatile("s_waitcnt vmcnt(0)" ::: "memory");
            __builtin_amdgcn_sched_barrier(0);
            __builtin_amdgcn_s_barrier();
            __builtin_amdgcn_sched_barrier(0);
        }
    }
#undef LOADED
#undef STAGE_B
#undef GELU_A

    // ---- epilogue via per-wave LDS pad: 16 rows x 76 f32 (4864 B/wave, 38.9KB tot)
    asm volatile("s_waitcnt lgkmcnt(0)" ::: "memory");
    __builtin_amdgcn_sched_barrier(0);
    __builtin_amdgcn_s_barrier();          // all waves done reading As/Bs -> LDS reusable
    __builtin_amdgcn_sched_barrier(0);

    char* ep = lds + w * 4864;
#pragma unroll
    for (int mi = 0; mi < 4; mi++) {
        // scatter acc into row-major pad (C/D layout: col=l15, row=lg*4+q); <=2-way banks
#pragma unroll
        for (int ni = 0; ni < 4; ni++)
#pragma unroll
            for (int q = 0; q < 4; q++)
                *(float*)(ep + (lg * 4 + q) * 304 + (ni * 16 + l15) * 4) = acc[mi][ni][q];
        asm volatile("s_waitcnt lgkmcnt(0)" ::: "memory");
        __builtin_amdgcn_sched_barrier(0);
        // read back contiguous rows, 16B/lane -> 256B contiguous per 16-lane group
#pragma unroll
        for (int it = 0; it < 4; it++) {
            int r = it * 4 + lg;
            f32x4 v = *(const f32x4*)(ep + r * 304 + l15 * 16);
            size_t row = m0 + mi * 16 + r;
            float* o = out + row * 1024 + n0 + w * 64 + l15 * 4;
            __builtin_nontemporal_store(v, (f32x4*)o);
        }
        asm volatile("s_waitcnt lgkmcnt(0)" ::: "memory");   // reads done before next mi overwrite
        __builtin_amdgcn_sched_barrier(0);
    }
}

extern "C" void kernel_launch(void* const* d_in, const int* in_sizes, int n_in,
                              void* d_out, int out_size, void* d_ws, size_t ws_size,
                              hipStream_t stream) {
    const float* enc = (const float*)d_in[0];   // (4,256,512)
    const float* dec = (const float*)d_in[1];   // (4,96,512)
    const float* W1  = (const float*)d_in[2];   // (1024,512)
    const float* b1  = (const float*)d_in[3];   // (512,)
    const float* W2  = (const float*)d_in[4];   // (512,1024)
    float* out = (float*)d_out;                 // (4,256,96,1024) f32

    char* ws = (char*)d_ws;
    float* he = (float*)(ws);                               // 1024x512 f32 (b1 folded)
    float* hd = (float*)(ws + 2097152);                     //  384x512 f32
    unsigned short* Wet = (unsigned short*)(ws + 2883584);  // 512x512 bf16 swz
    unsigned short* Wdt = (unsigned short*)(ws + 3407872);  // 512x512 bf16 swz
    unsigned short* W2t = (unsigned short*)(ws + 3932160);  // 1024x512 bf16 swz

    transpose_wewd<<<dim3(8, 8, 2), 256, 0, stream>>>(W1, Wet, Wdt);
    prep2<<<304, 256, 0, stream>>>(enc, dec, W2, Wet, Wdt, b1, W2t, he, hd);
    joint_fused<<<dim3(1536, 2), 512, 0, stream>>>(he, hd, W2t, out);
}